// Round 3
// baseline (429.026 us; speedup 1.0000x reference)
//
#include <hip/hip_runtime.h>
#include <hip/hip_bf16.h>

#define IN_F 256
#define NN   2048
#define BB   8
#define NEGV (-9.0e15f)

typedef unsigned short u16;
typedef unsigned long long u64;
typedef __attribute__((ext_vector_type(8))) short short8x;   // 8 bf16 = 4 VGPRs
typedef __attribute__((ext_vector_type(4))) float float4x;   // MFMA acc

// fp32 -> bf16 bits, round-to-nearest-even
__device__ __forceinline__ u16 f2b(float f) {
    union { float f; unsigned int u; } x; x.f = f;
    unsigned int r = x.u + 0x7FFFu + ((x.u >> 16) & 1u);
    return (u16)(r >> 16);
}

// ---------------------------------------------------------------------------
// prep: fused transposes (h->HbfT, lrgt1->GbfT, W1->W1T, W2->W2T) + calc_v.
// ---------------------------------------------------------------------------
__device__ __forceinline__ void transp_body(const float* __restrict__ src,
                                            u16* __restrict__ dst,
                                            int R, int C, int tid,
                                            float (*tile)[33])
{
    const int per = (R / 32) * (C / 32);
    const int b  = tid / per;
    const int tt = tid % per;
    const int jt = tt / (C / 32);
    const int ct = tt % (C / 32);
    src += (long)b * R * C;
    dst += (long)b * R * C;

    const int tx = threadIdx.x & 31, ty = threadIdx.x >> 5;
#pragma unroll
    for (int i = 0; i < 4; ++i)
        tile[ty + i * 8][tx] = src[(long)(jt * 32 + ty + i * 8) * C + ct * 32 + tx];
    __syncthreads();
#pragma unroll
    for (int i = 0; i < 4; ++i)
        dst[(long)(ct * 32 + ty + i * 8) * R + jt * 32 + tx] = f2b(tile[tx][ty + i * 8]);
}

__global__ __launch_bounds__(256) void prep(const float* __restrict__ h,
                                            const float* __restrict__ g,
                                            const float* __restrict__ W1,
                                            const float* __restrict__ W2,
                                            const float* __restrict__ a,
                                            u16* __restrict__ HbfT,
                                            u16* __restrict__ GbfT,
                                            u16* __restrict__ W1T,
                                            u16* __restrict__ W2T,
                                            float* __restrict__ v1,
                                            float* __restrict__ v2)
{
    __shared__ float tile[32][33];
    __shared__ float s1[IN_F], s2[IN_F];
    const int bid = blockIdx.x;

    if (bid < 4096) {
        transp_body(h, HbfT, NN, IN_F, bid, tile);
    } else if (bid < 8192) {
        transp_body(g, GbfT, NN, IN_F, bid - 4096, tile);
    } else if (bid < 8256) {
        transp_body(W1, W1T, IN_F, IN_F, bid - 8192, tile);
    } else if (bid < 8320) {
        transp_body(W2, W2T, IN_F, IN_F, bid - 8256, tile);
    } else {
        const int t = threadIdx.x;
        s1[t] = a[t];
        s2[t] = a[IN_F + t];
        __syncthreads();
        float acc1 = 0.f, acc2 = 0.f;
        for (int c = 0; c < IN_F; ++c) {
            float w = W1[t * IN_F + c];
            acc1 += w * s1[c];
            acc2 += w * s2[c];
        }
        v1[t] = acc1;
        v2[t] = acc2;
    }
}

// ---------------------------------------------------------------------------
// rowdots: Wh1[row] = h[row,:]·v1, Wh2[row] = h[row,:]·v2. One wave per row.
// ---------------------------------------------------------------------------
__global__ __launch_bounds__(256) void rowdots(const float* __restrict__ h,
                                               const float* __restrict__ v1,
                                               const float* __restrict__ v2,
                                               float* __restrict__ Wh1,
                                               float* __restrict__ Wh2)
{
    const int wave = threadIdx.x >> 6;
    const int lane = threadIdx.x & 63;
    const long row = (long)blockIdx.x * 4 + wave;
    const int c0 = lane * 4;

    float4 v  = *(const float4*)(h + row * IN_F + c0);
    float4 a1 = *(const float4*)(v1 + c0);
    float4 a2 = *(const float4*)(v2 + c0);

    float s1 = v.x * a1.x + v.y * a1.y + v.z * a1.z + v.w * a1.w;
    float s2 = v.x * a2.x + v.y * a2.y + v.z * a2.z + v.w * a2.w;
#pragma unroll
    for (int off = 32; off; off >>= 1) {
        s1 += __shfl_xor(s1, off, 64);
        s2 += __shfl_xor(s2, off, 64);
    }
    if (lane == 0) { Wh1[row] = s1; Wh2[row] = s2; }
}

// ---------------------------------------------------------------------------
// attn_mfma v4: adj out of the K-loop.
// Theory: vmcnt retires IN ORDER, so the per-chunk adj prefetch (HBM, ~900cy)
// poisoned every later B-load wait (L2, ~300cy) — each MFMA group's
// compiler-inserted vmcnt inherited HBM latency.  Fix:
//  * block prefix packs its 64 adj rows (512 KB) into a 16 KB LDS bitmask via
//    __ballot (streaming, BW-bound); in-loop mask access = 1 tiny ds_read.
//    The in-loop vm queue is then uniformly L2-latency (B panel + Wh2 only).
//  * B depth-4: all 4 kstep groups of chunk k+1 issued during chunk k's MFMA
//    phase (static period-4 register rotation G0..G3) -> ~full-chunk cover.
//  * A per-kstep ping-pong (Aa/Ab); p-compute+A-write for chunk k+1 placed
//    before the MFMA phase so the lgkm drain happens under MFMAs; single
//    lgkm-only barrier per chunk (vm loads stay in flight across it).
//  * s_setprio(1) around each 16-MFMA cluster.
// ---------------------------------------------------------------------------
#define AREAD(AR, KS)                                                         \
    _Pragma("unroll") for (int rt = 0; rt < 4; ++rt)                          \
        AR[rt] = *(const short8x*)&ab[((KS) * 4 + rt) * 512 + lane * 8];

#define MFMA16(AR, G)                                                         \
    _Pragma("unroll") for (int rt = 0; rt < 4; ++rt)                          \
        _Pragma("unroll") for (int ct = 0; ct < 4; ++ct)                      \
            acc[rt][ct] = __builtin_amdgcn_mfma_f32_16x16x32_bf16(AR[rt], G[ct], acc[rt][ct], 0, 0, 0);

#define BISSUE(G, KN, KS)                                                     \
    _Pragma("unroll") for (int ct = 0; ct < 4; ++ct)                          \
        G[ct] = *(const short8x*)(Bp + ct * 16 * NN + ((KN) * 128 + (KS) * 32 + bq8));

#define CHUNK2(KCH, W4C, W4N)                                                 \
    {                                                                         \
        const u16* ab = &Afrag[(KCH) & 1][0];                                 \
        u16* abn = &Afrag[((KCH) + 1) & 1][0];                                \
        AREAD(Aa, 0)                                                          \
        if ((KCH) < 15) {                                                     \
            const u64 mk = maskL[rr][((KCH) + 1) * 2 + (sg >> 2)];            \
            const unsigned int bits = (unsigned int)((mk >> ((sg & 3) * 16)) & 0xFFFFull); \
            union { short8x v; u16 e[8]; } pk0, pk1;                          \
            _Pragma("unroll") for (int u = 0; u < 4; ++u) {                   \
                const float wf[4] = {W4C[u].x, W4C[u].y, W4C[u].z, W4C[u].w}; \
                _Pragma("unroll") for (int c = 0; c < 4; ++c) {               \
                    float x = wh1rr + wf[c];                                  \
                    float ev = fmaxf(x, 0.2f * x);                            \
                    float p = __expf(ev - mv);                                \
                    p = ((bits >> (u * 4 + c)) & 1u) ? p : 0.0f;              \
                    lloc += p;                                                \
                    u16 fv = f2b(p);                                          \
                    if (u < 2) pk0.e[u * 4 + c] = fv;                         \
                    else       pk1.e[(u - 2) * 4 + c] = fv;                   \
                }                                                             \
            }                                                                 \
            *(short8x*)&abn[wbase0]       = pk0.v;                            \
            *(short8x*)&abn[wbase0 + 128] = pk1.v;                            \
            if ((KCH) < 14) {                                                 \
                _Pragma("unroll") for (int u = 0; u < 4; ++u)                 \
                    W4N[u] = *(const float4*)(wh2b + ((KCH) + 2) * 128 + sg * 16 + u * 4); \
            }                                                                 \
        }                                                                     \
        AREAD(Ab, 1)                                                          \
        __builtin_amdgcn_s_setprio(1);                                        \
        MFMA16(Aa, G0)                                                        \
        __builtin_amdgcn_s_setprio(0);                                        \
        if ((KCH) < 15) { BISSUE(G0, (KCH) + 1, 0) }                          \
        AREAD(Aa, 2)                                                          \
        __builtin_amdgcn_s_setprio(1);                                        \
        MFMA16(Ab, G1)                                                        \
        __builtin_amdgcn_s_setprio(0);                                        \
        if ((KCH) < 15) { BISSUE(G1, (KCH) + 1, 1) }                          \
        AREAD(Ab, 3)                                                          \
        __builtin_amdgcn_s_setprio(1);                                        \
        MFMA16(Aa, G2)                                                        \
        __builtin_amdgcn_s_setprio(0);                                        \
        if ((KCH) < 15) { BISSUE(G2, (KCH) + 1, 2) }                          \
        __builtin_amdgcn_s_setprio(1);                                        \
        MFMA16(Ab, G3)                                                        \
        __builtin_amdgcn_s_setprio(0);                                        \
        if ((KCH) < 15) { BISSUE(G3, (KCH) + 1, 3) }                          \
        asm volatile("s_waitcnt lgkmcnt(0)\n\ts_barrier" ::: "memory");       \
    }

__global__ __launch_bounds__(512, 2) void attn_mfma(
    const int* __restrict__ adj,
    const u16* __restrict__ HbfT, const u16* __restrict__ GbfT,
    const float* __restrict__ Wh1, const float* __restrict__ Wh2,
    u16* __restrict__ PH, u16* __restrict__ PG)
{
    const int t = threadIdx.x;
    const int wave = t >> 6, lane = t & 63;
    // batch-per-XCD swizzle: 256 blocks / 8 XCDs -> 32 blocks = 1 batch each
    const int bswz = ((blockIdx.x & 7) << 5) | (blockIdx.x >> 3);
    const int b = bswz >> 5;                  // 32 row-blocks per batch
    const long gi0 = (long)bswz * 64;         // global row base (BM=64)

    __shared__ __align__(16) u16 Afrag[2][8192];   // 2 x 16 KB (4 ksteps x 4 rt)
    __shared__ u64 maskL[64][32];                  // 16 KB adj bitmask
    __shared__ float sred[512];
    __shared__ float ssc[65];                      // [0..63]=1/l, [64]=wh2max

    // p-compute role: row rr (64 rows), segment sg (8) -> 16 consecutive j
    const int rr = t >> 3, sg = t & 7;
    const float* wh2b = Wh2 + (long)b * NN;
    const float wh1rr = Wh1[gi0 + rr];

    // ---- per-batch max of Wh2 (8 KB, L2-hot after this) ----
    {
        float4 w = *(const float4*)(wh2b + t * 4);
        sred[t] = fmaxf(fmaxf(w.x, w.y), fmaxf(w.z, w.w));
    }
    __syncthreads();
    if (t < 64) {
        float v = sred[t * 8];
#pragma unroll
        for (int k = 1; k < 8; ++k) v = fmaxf(v, sred[t * 8 + k]);
#pragma unroll
        for (int off = 32; off; off >>= 1) v = fmaxf(v, __shfl_xor(v, off, 64));
        if (t == 0) ssc[64] = v;
    }
    __syncthreads();
    const float mm = wh1rr + ssc[64];
    const float mv = (mm >= 0.f) ? mm : 0.2f * mm;   // lrelu upper bound >= all logits

    // ---- prefix: pack this block's 64 adj rows into the LDS bitmask ----
    // word w = row*32 + seg covers j in [seg*64, seg*64+64); bit l = lane l.
    {
        u64* maskW = &maskL[0][0];
#pragma unroll 8
        for (int it = 0; it < 256; ++it) {
            const int w = wave * 256 + it;
            const int row = w >> 5, seg = w & 31;
            const int v = adj[(gi0 + row) * (long)NN + seg * 64 + lane];
            const u64 m = __ballot(v > 0);
            if (lane == 0) maskW[w] = m;
        }
    }
    __syncthreads();

    // A-fragment write slot (16x16x32 A layout: lane = m + 16*(k>>3), 8 k/lane)
    const int wbase0 = ((sg >> 1) * 4 + (rr >> 4)) * 512
                     + ((rr & 15) + 16 * (2 * (sg & 1))) * 8;

    float4x acc[4][4];
#pragma unroll
    for (int rt = 0; rt < 4; ++rt)
#pragma unroll
        for (int ct = 0; ct < 4; ++ct) acc[rt][ct] = (float4x)0.0f;

    const int bn = lane & 15, bq = lane >> 4, bq8 = bq * 8;
    const long hbase = (long)b * IN_F * NN;
    // wave -> matrix + 64-col slice: waves 0-3 = H cols, 4-7 = G cols
    const u16* Bp = ((wave < 4) ? HbfT : GbfT) + hbase
                  + (long)((wave & 3) * 64 + bn) * NN;

    float lloc = 0.f;

    short8x Aa[4], Ab[4];
    short8x G0[4], G1[4], G2[4], G3[4];
    float4 w4A[4], w4B[4];

    // ---- prologue: p for chunk 0 -> buf0; w4 prefetch chunk 1; B chunk 0 ----
    {
        const u64 mk = maskL[rr][sg >> 2];
        const unsigned int bits = (unsigned int)((mk >> ((sg & 3) * 16)) & 0xFFFFull);
        union { short8x v; u16 e[8]; } pk0, pk1;
#pragma unroll
        for (int u = 0; u < 4; ++u) {
            const float4 wv = *(const float4*)(wh2b + sg * 16 + u * 4);
            const float wf[4] = {wv.x, wv.y, wv.z, wv.w};
#pragma unroll
            for (int c = 0; c < 4; ++c) {
                float x = wh1rr + wf[c];
                float ev = fmaxf(x, 0.2f * x);
                float p = __expf(ev - mv);
                p = ((bits >> (u * 4 + c)) & 1u) ? p : 0.0f;
                lloc += p;
                u16 fv = f2b(p);
                if (u < 2) pk0.e[u * 4 + c] = fv;
                else       pk1.e[(u - 2) * 4 + c] = fv;
            }
        }
        u16* ab0 = &Afrag[0][0];
        *(short8x*)&ab0[wbase0]       = pk0.v;
        *(short8x*)&ab0[wbase0 + 128] = pk1.v;
#pragma unroll
        for (int u = 0; u < 4; ++u)
            w4A[u] = *(const float4*)(wh2b + 128 + sg * 16 + u * 4);
        BISSUE(G0, 0, 0)
        BISSUE(G1, 0, 1)
        BISSUE(G2, 0, 2)
        BISSUE(G3, 0, 3)
        asm volatile("s_waitcnt lgkmcnt(0)\n\ts_barrier" ::: "memory");
    }

    for (int kp = 0; kp < 8; ++kp) {
        CHUNK2(kp * 2,     w4A, w4B)
        CHUNK2(kp * 2 + 1, w4B, w4A)
    }

    // ---- reduce l per row (8 partials/row), invert ----
    sred[t] = lloc;
    __syncthreads();
    if (t < 64) {
        float v = sred[t * 8];
#pragma unroll
        for (int k = 1; k < 8; ++k) v += sred[t * 8 + k];
        ssc[t] = 1.0f / v;       // v > 0 always (~half the j's unmasked)
    }
    __syncthreads();

    // ---- scale by 1/l and store (C-layout: col=lane&15, row=(lane>>4)*4+reg)
    u16* dst = (wave < 4) ? PH : PG;
    const int colb = (wave & 3) * 64;
#pragma unroll
    for (int rt = 0; rt < 4; ++rt)
#pragma unroll
        for (int ct = 0; ct < 4; ++ct) {
            const int c = colb + ct * 16 + bn;
#pragma unroll
            for (int reg = 0; reg < 4; ++reg) {
                const int rl = rt * 16 + bq * 4 + reg;
                const float il = ssc[rl];
                const long row = gi0 + rl;
                dst[row * IN_F + c] = f2b(acc[rt][ct][reg] * il);
            }
        }
}

// ---------------------------------------------------------------------------
// epi2: both epilogue GEMMs in one launch.
// blocks [0,512): out0 = ELU(PH @ W1); blocks [512,1024): out1 = ELU(PG @ W2)
// ---------------------------------------------------------------------------
__global__ __launch_bounds__(256) void epi2(const u16* __restrict__ PH,
                                            const u16* __restrict__ PG,
                                            const u16* __restrict__ W1T,
                                            const u16* __restrict__ W2T,
                                            float* __restrict__ out)
{
    int bid = blockIdx.x;
    const u16* X;
    const u16* WT;
    float* o;
    if (bid < 512) { X = PH; WT = W1T; o = out; }
    else           { X = PG; WT = W2T; o = out + (long)BB * NN * IN_F; bid -= 512; }

    const int t = threadIdx.x;
    const int wave = t >> 6, lane = t & 63;
    const long i0 = (long)bid * 32;

    __shared__ __align__(16) u16 Afrag[8 * 2 * 64 * 8];   // 16 KB

    const int m = t >> 3, ks0 = t & 7, rt0 = m >> 4, lm = m & 15;
    const u16* xp = X + (i0 + m) * IN_F + ks0 * 32;
#pragma unroll
    for (int q = 0; q < 4; ++q) {
        short8x v = *(const short8x*)(xp + q * 8);
        *(short8x*)&Afrag[((ks0 * 2 + rt0) * 64 + lm + q * 16) * 8] = v;
    }
    __syncthreads();

    float4x acc[2][4];
#pragma unroll
    for (int rt = 0; rt < 2; ++rt)
#pragma unroll
        for (int ct = 0; ct < 4; ++ct) acc[rt][ct] = (float4x)0.0f;

    const int bn = lane & 15, bq = lane >> 4;
#pragma unroll
    for (int ks = 0; ks < 8; ++ks) {
        short8x A0 = *(const short8x*)&Afrag[((ks * 2 + 0) * 64 + lane) * 8];
        short8x A1 = *(const short8x*)&Afrag[((ks * 2 + 1) * 64 + lane) * 8];
#pragma unroll
        for (int ct = 0; ct < 4; ++ct) {
            const int n = wave * 64 + ct * 16 + bn;
            short8x Bw = *(const short8x*)(WT + n * IN_F + ks * 32 + bq * 8);
            acc[0][ct] = __builtin_amdgcn_mfma_f32_16x16x32_bf16(A0, Bw, acc[0][ct], 0, 0, 0);
            acc[1][ct] = __builtin_amdgcn_mfma_f32_16x16x32_bf16(A1, Bw, acc[1][ct], 0, 0, 0);
        }
    }

#pragma unroll
    for (int rt = 0; rt < 2; ++rt)
#pragma unroll
        for (int ct = 0; ct < 4; ++ct) {
            const int n = wave * 64 + ct * 16 + bn;
#pragma unroll
            for (int reg = 0; reg < 4; ++reg) {
                const long row = i0 + rt * 16 + bq * 4 + reg;
                float v = acc[rt][ct][reg];
                v = (v > 0.f) ? v : (__expf(v) - 1.f);   // ELU
                o[row * IN_F + n] = v;
            }
        }
}

// ---------------------------------------------------------------------------
extern "C" void kernel_launch(void* const* d_in, const int* in_sizes, int n_in,
                              void* d_out, int out_size, void* d_ws, size_t ws_size,
                              hipStream_t stream)
{
    int ih = -1, ig = -1, iadj = -1, iw1 = -1, iw2 = -1, ia = -1;
    for (int i = 0; i < n_in; ++i) {
        int s = in_sizes[i];
        if      (s == BB * NN * NN)   { if (iadj < 0) iadj = i; }
        else if (s == BB * NN * IN_F) { if (ih < 0) ih = i; else if (ig < 0) ig = i; }
        else if (s == IN_F * IN_F)    { if (iw1 < 0) iw1 = i; else if (iw2 < 0) iw2 = i; }
        else if (s == 2 * IN_F)       { if (ia < 0) ia = i; }
    }
    if (ih < 0 || ig < 0 || iadj < 0 || iw1 < 0 || iw2 < 0 || ia < 0) {
        ih = 0; iadj = 1; ig = 2; iw1 = 3; iw2 = 4; ia = 5;
    }
    const float* h     = (const float*)d_in[ih];
    const int*   adj   = (const int*)  d_in[iadj];
    const float* lrgt1 = (const float*)d_in[ig];
    const float* W1    = (const float*)d_in[iw1];
    const float* W2    = (const float*)d_in[iw2];
    const float* a     = (const float*)d_in[ia];
    float* out = (float*)d_out;

    // ws layout — 33,949,696 B total (<= proven-available 34,212,096 B)
    float* ws   = (float*)d_ws;
    float* v1   = ws;                       // 256
    float* v2   = v1 + IN_F;                // 256
    float* Wh1  = v2 + IN_F;                // 16384
    float* Wh2  = Wh1 + BB * NN;            // 16384
    u16* W1T  = (u16*)(Wh2 + BB * NN);      // 65536 bf16
    u16* W2T  = W1T + IN_F * IN_F;          // 65536
    u16* HbfT = W2T + IN_F * IN_F;          // 8*256*2048
    u16* GbfT = HbfT + (long)BB * IN_F * NN;
    u16* PH   = GbfT + (long)BB * IN_F * NN;
    u16* PG   = PH + (long)BB * NN * IN_F;

    const int nrows = BB * NN;

    prep     <<<8321,        256, 0, stream>>>(h, lrgt1, W1, W2, a,
                                               HbfT, GbfT, W1T, W2T, v1, v2);
    rowdots  <<<nrows / 4,   256, 0, stream>>>(h, v1, v2, Wh1, Wh2);
    attn_mfma<<<nrows / 64,  512, 0, stream>>>(adj, HbfT, GbfT, Wh1, Wh2, PH, PG);
    epi2     <<<2 * nrows / 32, 256, 0, stream>>>(PH, PG, W1T, W2T, out);
}

// Round 4
// 345.365 us; speedup vs baseline: 1.2422x; 1.2422x over previous
//
#include <hip/hip_runtime.h>
#include <hip/hip_bf16.h>

#define IN_F 256
#define NN   2048
#define BB   8

typedef unsigned short u16;
typedef __attribute__((ext_vector_type(8))) short short8x;   // 8 bf16 = 4 VGPRs
typedef __attribute__((ext_vector_type(4))) float float4x;   // MFMA acc

// fp32 -> bf16 bits, round-to-nearest-even
__device__ __forceinline__ u16 f2b(float f) {
    union { float f; unsigned int u; } x; x.f = f;
    unsigned int r = x.u + 0x7FFFu + ((x.u >> 16) & 1u);
    return (u16)(r >> 16);
}

// ---------------------------------------------------------------------------
// prep: fused transposes (h->HbfT, lrgt1->GbfT, W1->W1T, W2->W2T) + calc_v.
// ---------------------------------------------------------------------------
__device__ __forceinline__ void transp_body(const float* __restrict__ src,
                                            u16* __restrict__ dst,
                                            int R, int C, int tid,
                                            float (*tile)[33])
{
    const int per = (R / 32) * (C / 32);
    const int b  = tid / per;
    const int tt = tid % per;
    const int jt = tt / (C / 32);
    const int ct = tt % (C / 32);
    src += (long)b * R * C;
    dst += (long)b * R * C;

    const int tx = threadIdx.x & 31, ty = threadIdx.x >> 5;
#pragma unroll
    for (int i = 0; i < 4; ++i)
        tile[ty + i * 8][tx] = src[(long)(jt * 32 + ty + i * 8) * C + ct * 32 + tx];
    __syncthreads();
#pragma unroll
    for (int i = 0; i < 4; ++i)
        dst[(long)(ct * 32 + ty + i * 8) * R + jt * 32 + tx] = f2b(tile[tx][ty + i * 8]);
}

__global__ __launch_bounds__(256) void prep(const float* __restrict__ h,
                                            const float* __restrict__ g,
                                            const float* __restrict__ W1,
                                            const float* __restrict__ W2,
                                            const float* __restrict__ a,
                                            u16* __restrict__ HbfT,
                                            u16* __restrict__ GbfT,
                                            u16* __restrict__ W1T,
                                            u16* __restrict__ W2T,
                                            float* __restrict__ v1,
                                            float* __restrict__ v2)
{
    __shared__ float tile[32][33];
    __shared__ float s1[IN_F], s2[IN_F];
    const int bid = blockIdx.x;

    if (bid < 4096) {
        transp_body(h, HbfT, NN, IN_F, bid, tile);
    } else if (bid < 8192) {
        transp_body(g, GbfT, NN, IN_F, bid - 4096, tile);
    } else if (bid < 8256) {
        transp_body(W1, W1T, IN_F, IN_F, bid - 8192, tile);
    } else if (bid < 8320) {
        transp_body(W2, W2T, IN_F, IN_F, bid - 8256, tile);
    } else {
        const int t = threadIdx.x;
        s1[t] = a[t];
        s2[t] = a[IN_F + t];
        __syncthreads();
        float acc1 = 0.f, acc2 = 0.f;
        for (int c = 0; c < IN_F; ++c) {
            float w = W1[t * IN_F + c];
            acc1 += w * s1[c];
            acc2 += w * s2[c];
        }
        v1[t] = acc1;
        v2[t] = acc2;
    }
}

// ---------------------------------------------------------------------------
// rowdots: Wh1[row] = h[row,:]·v1, Wh2[row] = h[row,:]·v2. One wave per row.
// ---------------------------------------------------------------------------
__global__ __launch_bounds__(256) void rowdots(const float* __restrict__ h,
                                               const float* __restrict__ v1,
                                               const float* __restrict__ v2,
                                               float* __restrict__ Wh1,
                                               float* __restrict__ Wh2)
{
    const int wave = threadIdx.x >> 6;
    const int lane = threadIdx.x & 63;
    const long row = (long)blockIdx.x * 4 + wave;
    const int c0 = lane * 4;

    float4 v  = *(const float4*)(h + row * IN_F + c0);
    float4 a1 = *(const float4*)(v1 + c0);
    float4 a2 = *(const float4*)(v2 + c0);

    float s1 = v.x * a1.x + v.y * a1.y + v.z * a1.z + v.w * a1.w;
    float s2 = v.x * a2.x + v.y * a2.y + v.z * a2.z + v.w * a2.w;
#pragma unroll
    for (int off = 32; off; off >>= 1) {
        s1 += __shfl_xor(s1, off, 64);
        s2 += __shfl_xor(s2, off, 64);
    }
    if (lane == 0) { Wh1[row] = s1; Wh2[row] = s2; }
}

// ---------------------------------------------------------------------------
// attn_mfma v5: v3 structure + in-order-vmcnt-safe prefetch positioning.
//  * NO setprio (v4's regression: prio boost starves the partner wave on a
//    2-wave/SIMD lockstep schedule -> SIMD serializes).
//  * NO adj prefix/bitmask (v4's other delta) — adj stays in-loop, but its
//    HBM prefetch is issued at the END of the chunk (after all B issues) at
//    distance 2: chunk K's tail issues adj/Wh2 for chunk K+2.  vmcnt retires
//    in order, so B-load waits never queue behind a fresh HBM adj load, and
//    the p-compute consuming adj_{K+1} has a full chunk of cover.
//  * B depth-4 rotation (G0..G3): B group for chunk K+1 kstep j is issued
//    right after the MFMA that consumes chunk K kstep j -> ~full-chunk cover.
//  * lgkm-only barrier per chunk (vm loads stay in flight across it).
// ---------------------------------------------------------------------------
#define AREAD(AR, KS)                                                         \
    _Pragma("unroll") for (int rt = 0; rt < 4; ++rt)                          \
        AR[rt] = *(const short8x*)&ab[((KS) * 4 + rt) * 512 + lane * 8];

#define MFMA16(AR, G)                                                         \
    _Pragma("unroll") for (int rt = 0; rt < 4; ++rt)                          \
        _Pragma("unroll") for (int ct = 0; ct < 4; ++ct)                      \
            acc[rt][ct] = __builtin_amdgcn_mfma_f32_16x16x32_bf16(AR[rt], G[ct], acc[rt][ct], 0, 0, 0);

#define BISSUE(G, KN, KS)                                                     \
    _Pragma("unroll") for (int ct = 0; ct < 4; ++ct)                          \
        G[ct] = *(const short8x*)(Bp + ct * 16 * NN + ((KN) * 128 + (KS) * 32 + bq8));

#define CHUNK3(KCH, ADJ, W4)                                                  \
    {                                                                         \
        union { short8x v; u16 e[8]; } pk0, pk1;                              \
        _Pragma("unroll") for (int u = 0; u < 4; ++u) {                       \
            const float wf[4] = {W4[u].x, W4[u].y, W4[u].z, W4[u].w};         \
            const int   av[4] = {ADJ[u].x, ADJ[u].y, ADJ[u].z, ADJ[u].w};     \
            _Pragma("unroll") for (int c = 0; c < 4; ++c) {                   \
                float x = wh1rr + wf[c];                                      \
                float ev = fmaxf(x, 0.2f * x);                                \
                float p = __expf(ev - mv);                                    \
                p = (av[c] > 0) ? p : 0.0f;                                   \
                lloc += p;                                                    \
                u16 fv = f2b(p);                                              \
                if (u < 2) pk0.e[u * 4 + c] = fv;                             \
                else       pk1.e[(u - 2) * 4 + c] = fv;                       \
            }                                                                 \
        }                                                                     \
        u16* ab = &Afrag[(KCH) & 1][0];                                       \
        *(short8x*)&ab[wbase0]       = pk0.v;                                 \
        *(short8x*)&ab[wbase0 + 128] = pk1.v;                                 \
        asm volatile("s_waitcnt lgkmcnt(0)\n\ts_barrier" ::: "memory");       \
        AREAD(Aa, 0)                                                          \
        AREAD(Ab, 1)                                                          \
        MFMA16(Aa, G0)                                                        \
        if ((KCH) < 15) { BISSUE(G0, (KCH) + 1, 0) }                          \
        AREAD(Aa, 2)                                                          \
        MFMA16(Ab, G1)                                                        \
        if ((KCH) < 15) { BISSUE(G1, (KCH) + 1, 1) }                          \
        AREAD(Ab, 3)                                                          \
        MFMA16(Aa, G2)                                                        \
        if ((KCH) < 15) { BISSUE(G2, (KCH) + 1, 2) }                          \
        MFMA16(Ab, G3)                                                        \
        if ((KCH) < 15) { BISSUE(G3, (KCH) + 1, 3) }                          \
        if ((KCH) < 14) {                                                     \
            const int jp = ((KCH) + 2) * 128 + sg * 16;                       \
            _Pragma("unroll") for (int u = 0; u < 4; ++u)                     \
                W4[u]  = *(const float4*)(wh2b + jp + u * 4);                 \
            _Pragma("unroll") for (int u = 0; u < 4; ++u)                     \
                ADJ[u] = *(const int4*)(adj + adjR + jp + u * 4);             \
        }                                                                     \
    }

__global__ __launch_bounds__(512, 2) void attn_mfma(
    const int* __restrict__ adj,
    const u16* __restrict__ HbfT, const u16* __restrict__ GbfT,
    const float* __restrict__ Wh1, const float* __restrict__ Wh2,
    u16* __restrict__ PH, u16* __restrict__ PG)
{
    const int t = threadIdx.x;
    const int wave = t >> 6, lane = t & 63;
    // batch-per-XCD swizzle: 256 blocks / 8 XCDs -> 32 blocks = 1 batch each
    const int bswz = ((blockIdx.x & 7) << 5) | (blockIdx.x >> 3);
    const int b = bswz >> 5;                  // 32 row-blocks per batch
    const long gi0 = (long)bswz * 64;         // global row base (BM=64)

    __shared__ __align__(16) u16 Afrag[2][8192];   // 2 x 16 KB (4 ksteps x 4 rt)
    __shared__ float sred[512];
    __shared__ float ssc[65];                      // [0..63]=1/l, [64]=wh2max

    // p-compute role: row rr (64 rows), segment sg (8) -> 16 consecutive j
    const int rr = t >> 3, sg = t & 7;
    const long adjR = (gi0 + rr) * (long)NN;
    const float* wh2b = Wh2 + (long)b * NN;
    const float wh1rr = Wh1[gi0 + rr];

    // ---- per-batch max of Wh2 (8 KB, L2-hot after this) ----
    {
        float4 w = *(const float4*)(wh2b + t * 4);
        sred[t] = fmaxf(fmaxf(w.x, w.y), fmaxf(w.z, w.w));
    }
    __syncthreads();
    if (t < 64) {
        float v = sred[t * 8];
#pragma unroll
        for (int k = 1; k < 8; ++k) v = fmaxf(v, sred[t * 8 + k]);
#pragma unroll
        for (int off = 32; off; off >>= 1) v = fmaxf(v, __shfl_xor(v, off, 64));
        if (t == 0) ssc[64] = v;
    }
    __syncthreads();
    const float mm = wh1rr + ssc[64];
    const float mv = (mm >= 0.f) ? mm : 0.2f * mm;   // lrelu upper bound >= all logits

    // A-fragment write slot (16x16x32 A layout: lane = m + 16*(k>>3), 8 k/lane)
    const int wbase0 = ((sg >> 1) * 4 + (rr >> 4)) * 512
                     + ((rr & 15) + 16 * (2 * (sg & 1))) * 8;

    float4x acc[4][4];
#pragma unroll
    for (int rt = 0; rt < 4; ++rt)
#pragma unroll
        for (int ct = 0; ct < 4; ++ct) acc[rt][ct] = (float4x)0.0f;

    const int bn = lane & 15, bq = lane >> 4, bq8 = bq * 8;
    const long hbase = (long)b * IN_F * NN;
    // wave -> matrix + 64-col slice: waves 0-3 = H cols, 4-7 = G cols
    const u16* Bp = ((wave < 4) ? HbfT : GbfT) + hbase
                  + (long)((wave & 3) * 64 + bn) * NN;

    float lloc = 0.f;

    short8x Aa[4], Ab[4];
    short8x G0[4], G1[4], G2[4], G3[4];
    int4   adjA[4], adjB[4];
    float4 w4A[4], w4B[4];

    // ---- prologue: adj/Wh2 for chunks 0 and 1; B groups for chunk 0 ----
#pragma unroll
    for (int u = 0; u < 4; ++u) {
        w4A[u]  = *(const float4*)(wh2b + sg * 16 + u * 4);
        adjA[u] = *(const int4*)(adj + adjR + sg * 16 + u * 4);
    }
#pragma unroll
    for (int u = 0; u < 4; ++u) {
        w4B[u]  = *(const float4*)(wh2b + 128 + sg * 16 + u * 4);
        adjB[u] = *(const int4*)(adj + adjR + 128 + sg * 16 + u * 4);
    }
    BISSUE(G0, 0, 0)
    BISSUE(G1, 0, 1)
    BISSUE(G2, 0, 2)
    BISSUE(G3, 0, 3)

    for (int kp = 0; kp < 8; ++kp) {
        CHUNK3(kp * 2,     adjA, w4A)
        CHUNK3(kp * 2 + 1, adjB, w4B)
    }

    // ---- reduce l per row (8 partials/row), invert ----
    sred[t] = lloc;
    __syncthreads();
    if (t < 64) {
        float v = sred[t * 8];
#pragma unroll
        for (int k = 1; k < 8; ++k) v += sred[t * 8 + k];
        ssc[t] = 1.0f / v;       // v > 0 always (~half the j's unmasked)
    }
    __syncthreads();

    // ---- scale by 1/l and store (C-layout: col=lane&15, row=(lane>>4)*4+reg)
    u16* dst = (wave < 4) ? PH : PG;
    const int colb = (wave & 3) * 64;
#pragma unroll
    for (int rt = 0; rt < 4; ++rt)
#pragma unroll
        for (int ct = 0; ct < 4; ++ct) {
            const int c = colb + ct * 16 + bn;
#pragma unroll
            for (int reg = 0; reg < 4; ++reg) {
                const int rl = rt * 16 + bq * 4 + reg;
                const float il = ssc[rl];
                const long row = gi0 + rl;
                dst[row * IN_F + c] = f2b(acc[rt][ct][reg] * il);
            }
        }
}

// ---------------------------------------------------------------------------
// epi2: both epilogue GEMMs in one launch.
// blocks [0,512): out0 = ELU(PH @ W1); blocks [512,1024): out1 = ELU(PG @ W2)
// ---------------------------------------------------------------------------
__global__ __launch_bounds__(256) void epi2(const u16* __restrict__ PH,
                                            const u16* __restrict__ PG,
                                            const u16* __restrict__ W1T,
                                            const u16* __restrict__ W2T,
                                            float* __restrict__ out)
{
    int bid = blockIdx.x;
    const u16* X;
    const u16* WT;
    float* o;
    if (bid < 512) { X = PH; WT = W1T; o = out; }
    else           { X = PG; WT = W2T; o = out + (long)BB * NN * IN_F; bid -= 512; }

    const int t = threadIdx.x;
    const int wave = t >> 6, lane = t & 63;
    const long i0 = (long)bid * 32;

    __shared__ __align__(16) u16 Afrag[8 * 2 * 64 * 8];   // 16 KB

    const int m = t >> 3, ks0 = t & 7, rt0 = m >> 4, lm = m & 15;
    const u16* xp = X + (i0 + m) * IN_F + ks0 * 32;
#pragma unroll
    for (int q = 0; q < 4; ++q) {
        short8x v = *(const short8x*)(xp + q * 8);
        *(short8x*)&Afrag[((ks0 * 2 + rt0) * 64 + lm + q * 16) * 8] = v;
    }
    __syncthreads();

    float4x acc[2][4];
#pragma unroll
    for (int rt = 0; rt < 2; ++rt)
#pragma unroll
        for (int ct = 0; ct < 4; ++ct) acc[rt][ct] = (float4x)0.0f;

    const int bn = lane & 15, bq = lane >> 4;
#pragma unroll
    for (int ks = 0; ks < 8; ++ks) {
        short8x A0 = *(const short8x*)&Afrag[((ks * 2 + 0) * 64 + lane) * 8];
        short8x A1 = *(const short8x*)&Afrag[((ks * 2 + 1) * 64 + lane) * 8];
#pragma unroll
        for (int ct = 0; ct < 4; ++ct) {
            const int n = wave * 64 + ct * 16 + bn;
            short8x Bw = *(const short8x*)(WT + n * IN_F + ks * 32 + bq * 8);
            acc[0][ct] = __builtin_amdgcn_mfma_f32_16x16x32_bf16(A0, Bw, acc[0][ct], 0, 0, 0);
            acc[1][ct] = __builtin_amdgcn_mfma_f32_16x16x32_bf16(A1, Bw, acc[1][ct], 0, 0, 0);
        }
    }

#pragma unroll
    for (int rt = 0; rt < 2; ++rt)
#pragma unroll
        for (int ct = 0; ct < 4; ++ct) {
            const int n = wave * 64 + ct * 16 + bn;
#pragma unroll
            for (int reg = 0; reg < 4; ++reg) {
                const long row = i0 + rt * 16 + bq * 4 + reg;
                float v = acc[rt][ct][reg];
                v = (v > 0.f) ? v : (__expf(v) - 1.f);   // ELU
                o[row * IN_F + n] = v;
            }
        }
}

// ---------------------------------------------------------------------------
extern "C" void kernel_launch(void* const* d_in, const int* in_sizes, int n_in,
                              void* d_out, int out_size, void* d_ws, size_t ws_size,
                              hipStream_t stream)
{
    int ih = -1, ig = -1, iadj = -1, iw1 = -1, iw2 = -1, ia = -1;
    for (int i = 0; i < n_in; ++i) {
        int s = in_sizes[i];
        if      (s == BB * NN * NN)   { if (iadj < 0) iadj = i; }
        else if (s == BB * NN * IN_F) { if (ih < 0) ih = i; else if (ig < 0) ig = i; }
        else if (s == IN_F * IN_F)    { if (iw1 < 0) iw1 = i; else if (iw2 < 0) iw2 = i; }
        else if (s == 2 * IN_F)       { if (ia < 0) ia = i; }
    }
    if (ih < 0 || ig < 0 || iadj < 0 || iw1 < 0 || iw2 < 0 || ia < 0) {
        ih = 0; iadj = 1; ig = 2; iw1 = 3; iw2 = 4; ia = 5;
    }
    const float* h     = (const float*)d_in[ih];
    const int*   adj   = (const int*)  d_in[iadj];
    const float* lrgt1 = (const float*)d_in[ig];
    const float* W1    = (const float*)d_in[iw1];
    const float* W2    = (const float*)d_in[iw2];
    const float* a     = (const float*)d_in[ia];
    float* out = (float*)d_out;

    // ws layout — 33,949,696 B total (<= proven-available 34,212,096 B)
    float* ws   = (float*)d_ws;
    float* v1   = ws;                       // 256
    float* v2   = v1 + IN_F;                // 256
    float* Wh1  = v2 + IN_F;                // 16384
    float* Wh2  = Wh1 + BB * NN;            // 16384
    u16* W1T  = (u16*)(Wh2 + BB * NN);      // 65536 bf16
    u16* W2T  = W1T + IN_F * IN_F;          // 65536
    u16* HbfT = W2T + IN_F * IN_F;          // 8*256*2048
    u16* GbfT = HbfT + (long)BB * IN_F * NN;
    u16* PH   = GbfT + (long)BB * IN_F * NN;
    u16* PG   = PH + (long)BB * NN * IN_F;

    const int nrows = BB * NN;

    prep     <<<8321,        256, 0, stream>>>(h, lrgt1, W1, W2, a,
                                               HbfT, GbfT, W1T, W2T, v1, v2);
    rowdots  <<<nrows / 4,   256, 0, stream>>>(h, v1, v2, Wh1, Wh2);
    attn_mfma<<<nrows / 64,  512, 0, stream>>>(adj, HbfT, GbfT, Wh1, Wh2, PH, PG);
    epi2     <<<2 * nrows / 32, 256, 0, stream>>>(PH, PG, W1T, W2T, out);
}

// Round 5
// 313.617 us; speedup vs baseline: 1.3680x; 1.1012x over previous
//
#include <hip/hip_runtime.h>
#include <hip/hip_bf16.h>

#define IN_F 256
#define NN   2048
#define BB   8

typedef unsigned short u16;
typedef __attribute__((ext_vector_type(8))) short short8x;   // 8 bf16 = 4 VGPRs
typedef __attribute__((ext_vector_type(4))) float float4x;   // MFMA acc

// fp32 -> bf16 bits, round-to-nearest-even
__device__ __forceinline__ u16 f2b(float f) {
    union { float f; unsigned int u; } x; x.f = f;
    unsigned int r = x.u + 0x7FFFu + ((x.u >> 16) & 1u);
    return (u16)(r >> 16);
}

// ---------------------------------------------------------------------------
// prep: fused transposes (h->HbfT, lrgt1->GbfT, W1->W1T, W2->W2T) + calc_v.
// ---------------------------------------------------------------------------
__device__ __forceinline__ void transp_body(const float* __restrict__ src,
                                            u16* __restrict__ dst,
                                            int R, int C, int tid,
                                            float (*tile)[33])
{
    const int per = (R / 32) * (C / 32);
    const int b  = tid / per;
    const int tt = tid % per;
    const int jt = tt / (C / 32);
    const int ct = tt % (C / 32);
    src += (long)b * R * C;
    dst += (long)b * R * C;

    const int tx = threadIdx.x & 31, ty = threadIdx.x >> 5;
#pragma unroll
    for (int i = 0; i < 4; ++i)
        tile[ty + i * 8][tx] = src[(long)(jt * 32 + ty + i * 8) * C + ct * 32 + tx];
    __syncthreads();
#pragma unroll
    for (int i = 0; i < 4; ++i)
        dst[(long)(ct * 32 + ty + i * 8) * R + jt * 32 + tx] = f2b(tile[tx][ty + i * 8]);
}

__global__ __launch_bounds__(256) void prep(const float* __restrict__ h,
                                            const float* __restrict__ g,
                                            const float* __restrict__ W1,
                                            const float* __restrict__ W2,
                                            const float* __restrict__ a,
                                            u16* __restrict__ HbfT,
                                            u16* __restrict__ GbfT,
                                            u16* __restrict__ W1T,
                                            u16* __restrict__ W2T,
                                            float* __restrict__ v1,
                                            float* __restrict__ v2)
{
    __shared__ float tile[32][33];
    __shared__ float s1[IN_F], s2[IN_F];
    const int bid = blockIdx.x;

    if (bid < 4096) {
        transp_body(h, HbfT, NN, IN_F, bid, tile);
    } else if (bid < 8192) {
        transp_body(g, GbfT, NN, IN_F, bid - 4096, tile);
    } else if (bid < 8256) {
        transp_body(W1, W1T, IN_F, IN_F, bid - 8192, tile);
    } else if (bid < 8320) {
        transp_body(W2, W2T, IN_F, IN_F, bid - 8256, tile);
    } else {
        const int t = threadIdx.x;
        s1[t] = a[t];
        s2[t] = a[IN_F + t];
        __syncthreads();
        float acc1 = 0.f, acc2 = 0.f;
        for (int c = 0; c < IN_F; ++c) {
            float w = W1[t * IN_F + c];
            acc1 += w * s1[c];
            acc2 += w * s2[c];
        }
        v1[t] = acc1;
        v2[t] = acc2;
    }
}

// ---------------------------------------------------------------------------
// rowdots: Wh1[row] = h[row,:]·v1, Wh2[row] = h[row,:]·v2. One wave per row.
// ---------------------------------------------------------------------------
__global__ __launch_bounds__(256) void rowdots(const float* __restrict__ h,
                                               const float* __restrict__ v1,
                                               const float* __restrict__ v2,
                                               float* __restrict__ Wh1,
                                               float* __restrict__ Wh2)
{
    const int wave = threadIdx.x >> 6;
    const int lane = threadIdx.x & 63;
    const long row = (long)blockIdx.x * 4 + wave;
    const int c0 = lane * 4;

    float4 v  = *(const float4*)(h + row * IN_F + c0);
    float4 a1 = *(const float4*)(v1 + c0);
    float4 a2 = *(const float4*)(v2 + c0);

    float s1 = v.x * a1.x + v.y * a1.y + v.z * a1.z + v.w * a1.w;
    float s2 = v.x * a2.x + v.y * a2.y + v.z * a2.z + v.w * a2.w;
#pragma unroll
    for (int off = 32; off; off >>= 1) {
        s1 += __shfl_xor(s1, off, 64);
        s2 += __shfl_xor(s2, off, 64);
    }
    if (lane == 0) { Wh1[row] = s1; Wh2[row] = s2; }
}

// ---------------------------------------------------------------------------
// attn_mfma v6: EXACTLY v3 (the 101 us version) with ONE delta — the
// adj/Wh2 prefetch moves from mid-chunk (issued BEFORE all of the chunk's
// B-panel issues) to END-of-chunk at distance 2 (issued AFTER the chunk's
// last B issue, consumed two chunks later).
// Rationale: vmcnt retires IN ORDER.  In v3 the fresh adj HBM load sat in
// the vm queue ahead of the chunk's B loads, so every compiler-inserted
// B-wait inherited adj's HBM latency (~900+cy under 128MB chip-wide adj
// streaming).  With the adj load issued after all same-chunk B issues:
//   - B(K,*) waits drain only loads older than adj(K+2)  -> L2 latency only
//   - B(K+1,g0) (issued just before adj(K+2)) likewise
//   - adj(K+2) itself is consumed 2 chunks (~10k cy) later -> fully covered
// Register pressure is IDENTICAL to v3 (same two parity buffers; distance-2
// just means a parity buffer self-overwrites after its chunk consumed it).
// No setprio (v4 lesson), no depth-4 B (v5 spill lesson).
// A single sched_barrier(0) pins the prefetch below the B issues.
// ---------------------------------------------------------------------------
#define KSTEP(ksv, BC, BN_, AC, AN_, do_a, jnxt)                              \
    {                                                                         \
        if (do_a) {                                                           \
            _Pragma("unroll") for (int rt = 0; rt < 4; ++rt)                  \
                AN_[rt] = *(const short8x*)&ab[(((ksv) + 1) * 4 + rt) * 512 + lane * 8]; \
        }                                                                     \
        _Pragma("unroll") for (int ct = 0; ct < 4; ++ct)                      \
            BN_[ct] = *(const short8x*)(Bp + ct * 16 * NN + (jnxt));          \
        _Pragma("unroll") for (int rt = 0; rt < 4; ++rt)                      \
            _Pragma("unroll") for (int ct = 0; ct < 4; ++ct)                  \
                acc[rt][ct] = __builtin_amdgcn_mfma_f32_16x16x32_bf16(AC[rt], BC[ct], acc[rt][ct], 0, 0, 0); \
    }

#define CHUNKD2(KCH, ADJ, W4)                                                 \
    {                                                                         \
        const int j0 = (KCH) * 128;                                           \
        union { short8x v; u16 e[8]; } pk0, pk1;                              \
        _Pragma("unroll") for (int u = 0; u < 4; ++u) {                       \
            const float wf[4] = {W4[u].x, W4[u].y, W4[u].z, W4[u].w};         \
            const int   av[4] = {ADJ[u].x, ADJ[u].y, ADJ[u].z, ADJ[u].w};     \
            _Pragma("unroll") for (int c = 0; c < 4; ++c) {                   \
                float x = wh1rr + wf[c];                                      \
                float e = fmaxf(x, 0.2f * x);                                 \
                float p = __expf(e - mv);                                     \
                p = (av[c] > 0) ? p : 0.0f;                                   \
                lloc += p;                                                    \
                u16 fv = f2b(p);                                              \
                if (u < 2) pk0.e[u * 4 + c] = fv;                             \
                else       pk1.e[(u - 2) * 4 + c] = fv;                       \
            }                                                                 \
        }                                                                     \
        u16* ab = &Afrag[(KCH) & 1][0];                                       \
        *(short8x*)&ab[wbase0]       = pk0.v;                                 \
        *(short8x*)&ab[wbase0 + 128] = pk1.v;                                 \
        asm volatile("s_waitcnt lgkmcnt(0)\n\ts_barrier" ::: "memory");       \
        _Pragma("unroll") for (int rt = 0; rt < 4; ++rt)                      \
            A0[rt] = *(const short8x*)&ab[rt * 512 + lane * 8];               \
        KSTEP(0, B0, B1, A0, A1, 1, j0 + 1 * 32 + bq8)                        \
        KSTEP(1, B1, B0, A1, A0, 1, j0 + 2 * 32 + bq8)                        \
        KSTEP(2, B0, B1, A0, A1, 1, j0 + 3 * 32 + bq8)                        \
        KSTEP(3, B1, B0, A1, A0, 0, (((KCH) < 15) ? (j0 + 128) : j0) + bq8)   \
        if ((KCH) < 14) {                                                     \
            __builtin_amdgcn_sched_barrier(0);                                \
            const int jp = ((KCH) + 2) * 128 + sg * 16;                       \
            _Pragma("unroll") for (int u = 0; u < 4; ++u)                     \
                W4[u]  = *(const float4*)(wh2b + jp + u * 4);                 \
            _Pragma("unroll") for (int u = 0; u < 4; ++u)                     \
                ADJ[u] = *(const int4*)(adj + adjR + jp + u * 4);             \
        }                                                                     \
    }

__global__ __launch_bounds__(512, 2) void attn_mfma(
    const int* __restrict__ adj,
    const u16* __restrict__ HbfT, const u16* __restrict__ GbfT,
    const float* __restrict__ Wh1, const float* __restrict__ Wh2,
    u16* __restrict__ PH, u16* __restrict__ PG)
{
    const int t = threadIdx.x;
    const int wave = t >> 6, lane = t & 63;
    // batch-per-XCD swizzle: 256 blocks / 8 XCDs -> 32 blocks = 1 batch each
    const int bswz = ((blockIdx.x & 7) << 5) | (blockIdx.x >> 3);
    const int b = bswz >> 5;                  // 32 row-blocks per batch
    const long gi0 = (long)bswz * 64;         // global row base (BM=64)

    __shared__ __align__(16) u16 Afrag[2][8192];   // 2 x 16 KB (4 ksteps x 4 rt)
    __shared__ float sred[512];
    __shared__ float ssc[65];                      // [0..63]=1/l, [64]=wh2max

    // p-compute role: row rr (64 rows), segment sg (8) -> 16 consecutive j
    const int rr = t >> 3, sg = t & 7;
    const long adjR = (gi0 + rr) * (long)NN;
    const float* wh2b = Wh2 + (long)b * NN;
    const float wh1rr = Wh1[gi0 + rr];

    // ---- per-batch max of Wh2 (8 KB, L2-hot after this) ----
    {
        float4 w = *(const float4*)(wh2b + t * 4);
        sred[t] = fmaxf(fmaxf(w.x, w.y), fmaxf(w.z, w.w));
    }
    __syncthreads();
    if (t < 64) {
        float v = sred[t * 8];
#pragma unroll
        for (int k = 1; k < 8; ++k) v = fmaxf(v, sred[t * 8 + k]);
#pragma unroll
        for (int off = 32; off; off >>= 1) v = fmaxf(v, __shfl_xor(v, off, 64));
        if (t == 0) ssc[64] = v;
    }
    __syncthreads();
    const float mm = wh1rr + ssc[64];
    const float mv = (mm >= 0.f) ? mm : 0.2f * mm;   // lrelu upper bound >= all logits

    // A-fragment write slot (16x16x32 A layout: lane = m + 16*(k>>3), 8 k/lane)
    const int wbase0 = ((sg >> 1) * 4 + (rr >> 4)) * 512
                     + ((rr & 15) + 16 * (2 * (sg & 1))) * 8;

    float4x acc[4][4];
#pragma unroll
    for (int rt = 0; rt < 4; ++rt)
#pragma unroll
        for (int ct = 0; ct < 4; ++ct) acc[rt][ct] = (float4x)0.0f;

    const int bn = lane & 15, bq = lane >> 4, bq8 = bq * 8;
    const long hbase = (long)b * IN_F * NN;
    // wave -> matrix + 64-col slice: waves 0-3 = H cols, 4-7 = G cols
    const u16* Bp = ((wave < 4) ? HbfT : GbfT) + hbase
                  + (long)((wave & 3) * 64 + bn) * NN;

    float lloc = 0.f;

    short8x A0[4], A1[4], B0[4], B1[4];
    int4   adjA[4], adjB[4];
    float4 w4A[4], w4B[4];

    // ---- prologue: adj/Wh2 for chunks 0 AND 1 (distance-2 steady state);
    //      B group (kch=0, ks=0) ----
#pragma unroll
    for (int u = 0; u < 4; ++u) {
        w4A[u]  = *(const float4*)(wh2b + sg * 16 + u * 4);
        adjA[u] = *(const int4*)(adj + adjR + sg * 16 + u * 4);
    }
#pragma unroll
    for (int u = 0; u < 4; ++u) {
        w4B[u]  = *(const float4*)(wh2b + 128 + sg * 16 + u * 4);
        adjB[u] = *(const int4*)(adj + adjR + 128 + sg * 16 + u * 4);
    }
#pragma unroll
    for (int ct = 0; ct < 4; ++ct)
        B0[ct] = *(const short8x*)(Bp + ct * 16 * NN + bq8);

    for (int kp = 0; kp < 8; ++kp) {
        CHUNKD2(kp * 2,     adjA, w4A)
        CHUNKD2(kp * 2 + 1, adjB, w4B)
    }

    // ---- reduce l per row (8 partials/row), invert ----
    sred[t] = lloc;
    __syncthreads();
    if (t < 64) {
        float v = sred[t * 8];
#pragma unroll
        for (int k = 1; k < 8; ++k) v += sred[t * 8 + k];
        ssc[t] = 1.0f / v;       // v > 0 always (~half the j's unmasked)
    }
    __syncthreads();

    // ---- scale by 1/l and store (C-layout: col=lane&15, row=(lane>>4)*4+reg)
    u16* dst = (wave < 4) ? PH : PG;
    const int colb = (wave & 3) * 64;
#pragma unroll
    for (int rt = 0; rt < 4; ++rt)
#pragma unroll
        for (int ct = 0; ct < 4; ++ct) {
            const int c = colb + ct * 16 + bn;
#pragma unroll
            for (int reg = 0; reg < 4; ++reg) {
                const int rl = rt * 16 + bq * 4 + reg;
                const float il = ssc[rl];
                const long row = gi0 + rl;
                dst[row * IN_F + c] = f2b(acc[rt][ct][reg] * il);
            }
        }
}

// ---------------------------------------------------------------------------
// epi2: both epilogue GEMMs in one launch.
// blocks [0,512): out0 = ELU(PH @ W1); blocks [512,1024): out1 = ELU(PG @ W2)
// ---------------------------------------------------------------------------
__global__ __launch_bounds__(256) void epi2(const u16* __restrict__ PH,
                                            const u16* __restrict__ PG,
                                            const u16* __restrict__ W1T,
                                            const u16* __restrict__ W2T,
                                            float* __restrict__ out)
{
    int bid = blockIdx.x;
    const u16* X;
    const u16* WT;
    float* o;
    if (bid < 512) { X = PH; WT = W1T; o = out; }
    else           { X = PG; WT = W2T; o = out + (long)BB * NN * IN_F; bid -= 512; }

    const int t = threadIdx.x;
    const int wave = t >> 6, lane = t & 63;
    const long i0 = (long)bid * 32;

    __shared__ __align__(16) u16 Afrag[8 * 2 * 64 * 8];   // 16 KB

    const int m = t >> 3, ks0 = t & 7, rt0 = m >> 4, lm = m & 15;
    const u16* xp = X + (i0 + m) * IN_F + ks0 * 32;
#pragma unroll
    for (int q = 0; q < 4; ++q) {
        short8x v = *(const short8x*)(xp + q * 8);
        *(short8x*)&Afrag[((ks0 * 2 + rt0) * 64 + lm + q * 16) * 8] = v;
    }
    __syncthreads();

    float4x acc[2][4];
#pragma unroll
    for (int rt = 0; rt < 2; ++rt)
#pragma unroll
        for (int ct = 0; ct < 4; ++ct) acc[rt][ct] = (float4x)0.0f;

    const int bn = lane & 15, bq = lane >> 4;
#pragma unroll
    for (int ks = 0; ks < 8; ++ks) {
        short8x A0 = *(const short8x*)&Afrag[((ks * 2 + 0) * 64 + lane) * 8];
        short8x A1 = *(const short8x*)&Afrag[((ks * 2 + 1) * 64 + lane) * 8];
#pragma unroll
        for (int ct = 0; ct < 4; ++ct) {
            const int n = wave * 64 + ct * 16 + bn;
            short8x Bw = *(const short8x*)(WT + n * IN_F + ks * 32 + bq * 8);
            acc[0][ct] = __builtin_amdgcn_mfma_f32_16x16x32_bf16(A0, Bw, acc[0][ct], 0, 0, 0);
            acc[1][ct] = __builtin_amdgcn_mfma_f32_16x16x32_bf16(A1, Bw, acc[1][ct], 0, 0, 0);
        }
    }

#pragma unroll
    for (int rt = 0; rt < 2; ++rt)
#pragma unroll
        for (int ct = 0; ct < 4; ++ct) {
            const int n = wave * 64 + ct * 16 + bn;
#pragma unroll
            for (int reg = 0; reg < 4; ++reg) {
                const long row = i0 + rt * 16 + bq * 4 + reg;
                float v = acc[rt][ct][reg];
                v = (v > 0.f) ? v : (__expf(v) - 1.f);   // ELU
                o[row * IN_F + n] = v;
            }
        }
}

// ---------------------------------------------------------------------------
extern "C" void kernel_launch(void* const* d_in, const int* in_sizes, int n_in,
                              void* d_out, int out_size, void* d_ws, size_t ws_size,
                              hipStream_t stream)
{
    int ih = -1, ig = -1, iadj = -1, iw1 = -1, iw2 = -1, ia = -1;
    for (int i = 0; i < n_in; ++i) {
        int s = in_sizes[i];
        if      (s == BB * NN * NN)   { if (iadj < 0) iadj = i; }
        else if (s == BB * NN * IN_F) { if (ih < 0) ih = i; else if (ig < 0) ig = i; }
        else if (s == IN_F * IN_F)    { if (iw1 < 0) iw1 = i; else if (iw2 < 0) iw2 = i; }
        else if (s == 2 * IN_F)       { if (ia < 0) ia = i; }
    }
    if (ih < 0 || ig < 0 || iadj < 0 || iw1 < 0 || iw2 < 0 || ia < 0) {
        ih = 0; iadj = 1; ig = 2; iw1 = 3; iw2 = 4; ia = 5;
    }
    const float* h     = (const float*)d_in[ih];
    const int*   adj   = (const int*)  d_in[iadj];
    const float* lrgt1 = (const float*)d_in[ig];
    const float* W1    = (const float*)d_in[iw1];
    const float* W2    = (const float*)d_in[iw2];
    const float* a     = (const float*)d_in[ia];
    float* out = (float*)d_out;

    // ws layout — 33,949,696 B total (<= proven-available 34,212,096 B)
    float* ws   = (float*)d_ws;
    float* v1   = ws;                       // 256
    float* v2   = v1 + IN_F;                // 256
    float* Wh1  = v2 + IN_F;                // 16384
    float* Wh2  = Wh1 + BB * NN;            // 16384
    u16* W1T  = (u16*)(Wh2 + BB * NN);      // 65536 bf16
    u16* W2T  = W1T + IN_F * IN_F;          // 65536
    u16* HbfT = W2T + IN_F * IN_F;          // 8*256*2048
    u16* GbfT = HbfT + (long)BB * IN_F * NN;
    u16* PH   = GbfT + (long)BB * IN_F * NN;
    u16* PG   = PH + (long)BB * NN * IN_F;

    const int nrows = BB * NN;

    prep     <<<8321,        256, 0, stream>>>(h, lrgt1, W1, W2, a,
                                               HbfT, GbfT, W1T, W2T, v1, v2);
    rowdots  <<<nrows / 4,   256, 0, stream>>>(h, v1, v2, Wh1, Wh2);
    attn_mfma<<<nrows / 64,  512, 0, stream>>>(adj, HbfT, GbfT, Wh1, Wh2, PH, PG);
    epi2     <<<2 * nrows / 32, 256, 0, stream>>>(PH, PG, W1T, W2T, out);
}